// Round 6
// baseline (361.582 us; speedup 1.0000x reference)
//
#include <hip/hip_runtime.h>

#define S_DIM 1024
#define TQ 8
#define LOG2E 1.44269504f

typedef __attribute__((ext_vector_type(4))) float f32x4;
typedef __attribute__((ext_vector_type(4))) int i32x4;
typedef _Float16 half4 __attribute__((ext_vector_type(4)));
typedef _Float16 half8 __attribute__((ext_vector_type(8)));

__device__ inline half8 pack8h(f32x4 a, f32x4 b) {
  half8 r;
  r[0] = (_Float16)a.x; r[1] = (_Float16)a.y;
  r[2] = (_Float16)a.z; r[3] = (_Float16)a.w;
  r[4] = (_Float16)b.x; r[5] = (_Float16)b.y;
  r[6] = (_Float16)b.z; r[7] = (_Float16)b.w;
  return r;
}

// ---------- prep: K -> f16 (same layout), V -> f16 transposed [bh][d][k] ----------
__global__ __launch_bounds__(256)
void prep_kernel(const float* __restrict__ kp, const float* __restrict__ vp,
                 _Float16* __restrict__ k16, _Float16* __restrict__ vt16)
{
  __shared__ _Float16 tile[64][72];
  const int tid = threadIdx.x;
  const int bh  = blockIdx.x >> 4;             // 32 (b,h) pairs
  const int c0  = (blockIdx.x & 15) * 64;      // 64-row k-chunk
  const size_t base = ((size_t)bh * S_DIM + c0) * 64;

  #pragma unroll
  for (int i = 0; i < 4; ++i) {
    const int idx = i * 256 + tid;
    f32x4 kv = *(const f32x4*)(kp + base + (size_t)idx * 4);
    half4 h; h[0] = (_Float16)kv.x; h[1] = (_Float16)kv.y;
    h[2] = (_Float16)kv.z; h[3] = (_Float16)kv.w;
    *(half4*)(k16 + base + (size_t)idx * 4) = h;
  }
  #pragma unroll
  for (int i = 0; i < 4; ++i) {
    const int idx = i * 256 + tid;
    const int r = idx >> 4, c4 = idx & 15;
    f32x4 vv = *(const f32x4*)(vp + base + (size_t)r * 64 + c4 * 4);
    tile[c4 * 4 + 0][r] = (_Float16)vv.x;
    tile[c4 * 4 + 1][r] = (_Float16)vv.y;
    tile[c4 * 4 + 2][r] = (_Float16)vv.z;
    tile[c4 * 4 + 3][r] = (_Float16)vv.w;
  }
  __syncthreads();
  #pragma unroll
  for (int i = 0; i < 2; ++i) {
    const int idx = i * 256 + tid;
    const int d = idx >> 3, g = idx & 7;
    half8 h = *(half8*)&tile[d][g * 8];
    *(half8*)(vt16 + ((size_t)bh * 64 + d) * S_DIM + c0 + g * 8) = h;
  }
}

// ---------- maskpack: mask[b][row][k] i32 -> pm[b*S+row][32] bit-dwords ----------
__global__ __launch_bounds__(256)
void maskpack_kernel(const int* __restrict__ maskp, unsigned int* __restrict__ pm)
{
  const int tid  = threadIdx.x;
  const int lane = tid & 63;
  const int wave = tid >> 6;
  const int row  = blockIdx.x;                 // 4096 rows (b*1024 + r)
  const size_t base = (size_t)row * S_DIM + wave * 256;
  unsigned long long bal0, bal1, bal2, bal3;
  bal0 = __ballot(maskp[base +   0 + lane] != 0);
  bal1 = __ballot(maskp[base +  64 + lane] != 0);
  bal2 = __ballot(maskp[base + 128 + lane] != 0);
  bal3 = __ballot(maskp[base + 192 + lane] != 0);
  if (lane == 0) {
    unsigned long long* dst =
        (unsigned long long*)(pm + (size_t)row * 32 + wave * 8);
    dst[0] = bal0; dst[1] = bal1; dst[2] = bal2; dst[3] = bal3;
  }
}

// ---------- main: TQ=8, 8 blocks/CU (100% wave occupancy), one barrier ----------
__global__ __launch_bounds__(256, 8)
void sdpa_kernel(const float* __restrict__ qp,
                 const _Float16* __restrict__ k16,
                 const _Float16* __restrict__ vt16,
                 const float* __restrict__ sphp,
                 const unsigned int* __restrict__ pm,
                 float* __restrict__ outp, float* __restrict__ pp)
{
  __shared__ _Float16 pb[TQ][1032];   // scores*log2e -> e (f16)   16512 B
  __shared__ float    red[4][TQ];     // per-wave row sums           128 B

  const int tid   = threadIdx.x;
  const int lane  = tid & 63;
  const int wave  = tid >> 6;
  const int row16 = lane & 15;        // MFMA m/n index
  const int quad  = lane >> 4;        // MFMA k-chunk / C row-quad
  const int row8  = row16 & 7;        // valid q within 8-row tile

  const int bh = blockIdx.x >> 7;     // 32 (b,h) pairs
  const int qt = blockIdx.x & 127;    // 128 q-tiles of 8 rows
  const int b  = bh >> 3;             // H=8
  const int q0 = qt * TQ;
  const size_t bhS = (size_t)bh * S_DIM;

  const int kb = wave * 256;          // wave-private 256-k span
  const int ll = lane & 31;           // phase-2: lane-in-half
  const int lh = lane >> 5;           // phase-2: row parity
  const int kcol2 = kb + ll * 8;      // phase-2: 8 k per lane

  // ---- mask bits for rows 0..7: 4 dwords (pm is L2-resident) ----
  const unsigned int* pmbase = pm + ((size_t)b * S_DIM + q0) * 32 + wave * 8 + (ll >> 2);
  unsigned int mb[4];
  #pragma unroll
  for (int i = 0; i < 4; ++i) mb[i] = pmbase[(size_t)(2 * i + lh) * 32];
  const int msh = (ll & 3) * 8;       // byte of 8 mask bits within dword

  // ---- sph bank A (rows 0..3): latency hides under all of phase 1 ----
  // Plain (cached) loads: sph is 134 MB < 256 MB L3 -> L3-resident across iters.
  f32x4 sA[2][2], sB[2][2];
  #pragma unroll
  for (int i = 0; i < 2; ++i) {
    const float* p = sphp + (bhS + q0 + 2 * i + lh) * S_DIM + kcol2;
    sA[i][0] = *(const f32x4*)p;
    sA[i][1] = *(const f32x4*)(p + 4);
  }

  // ---------- Phase 1: S^T = K (Q/8)^T via MFMA; scores*log2e -> pb (f16) -------
  // B cols 8..15 duplicate cols 0..7 (TQ=8); their outputs are discarded.
  const float* qrow = qp + (bhS + q0 + row8) * 64 + quad * 8;
  const f32x4 s8 = {0.125f, 0.125f, 0.125f, 0.125f};  // 1/TEMPERATURE
  f32x4 qa = *(const f32x4*)(qrow);
  f32x4 qb = *(const f32x4*)(qrow + 4);
  f32x4 qc = *(const f32x4*)(qrow + 32);
  f32x4 qd = *(const f32x4*)(qrow + 36);
  const half8 bq0 = pack8h(qa * s8, qb * s8);
  const half8 bq1 = pack8h(qc * s8, qd * s8);

  const _Float16* kbp = k16 + (bhS + kb) * 64;
  #pragma unroll
  for (int t = 0; t < 16; ++t) {
    const _Float16* krow = kbp + (t * 16 + row16) * 64 + quad * 8;
    half8 a0 = *(const half8*)(krow);
    half8 a1 = *(const half8*)(krow + 32);
    f32x4 acc = {0.f, 0.f, 0.f, 0.f};
    acc = __builtin_amdgcn_mfma_f32_16x16x32_f16(a0, bq0, acc, 0, 0, 0);
    acc = __builtin_amdgcn_mfma_f32_16x16x32_f16(a1, bq1, acc, 0, 0, 0);
    if (row16 < 8) {
      half4 hv;
      hv[0] = (_Float16)(acc.x * LOG2E); hv[1] = (_Float16)(acc.y * LOG2E);
      hv[2] = (_Float16)(acc.z * LOG2E); hv[3] = (_Float16)(acc.w * LOG2E);
      *(half4*)&pb[row16][kb + t * 16 + quad * 4] = hv;
    }
  }
  // NO barrier: phase 2 reads only this wave's own k-span of pb (same-wave order).

  // ---------- Phase 2: e = maskbit ? exp2(s2*sph) : 0 ; per-row sums ----------
  auto proc = [&](int i, const f32x4* sv, unsigned int mbi) {
    const int r = 2 * i + lh;
    half8 sh = *(half8*)&pb[r][kcol2];
    const unsigned int m = (mbi >> msh) & 0xFFu;
    float x0 = (float)sh[0] * sv[0].x, x1 = (float)sh[1] * sv[0].y;
    float x2 = (float)sh[2] * sv[0].z, x3 = (float)sh[3] * sv[0].w;
    float x4 = (float)sh[4] * sv[1].x, x5 = (float)sh[5] * sv[1].y;
    float x6 = (float)sh[6] * sv[1].z, x7 = (float)sh[7] * sv[1].w;
    float e0 = (m &   1u) ? __builtin_amdgcn_exp2f(x0) : 0.f;
    float e1 = (m &   2u) ? __builtin_amdgcn_exp2f(x1) : 0.f;
    float e2 = (m &   4u) ? __builtin_amdgcn_exp2f(x2) : 0.f;
    float e3 = (m &   8u) ? __builtin_amdgcn_exp2f(x3) : 0.f;
    float e4 = (m &  16u) ? __builtin_amdgcn_exp2f(x4) : 0.f;
    float e5 = (m &  32u) ? __builtin_amdgcn_exp2f(x5) : 0.f;
    float e6 = (m &  64u) ? __builtin_amdgcn_exp2f(x6) : 0.f;
    float e7 = (m & 128u) ? __builtin_amdgcn_exp2f(x7) : 0.f;
    half8 hv;
    hv[0] = (_Float16)e0; hv[1] = (_Float16)e1;
    hv[2] = (_Float16)e2; hv[3] = (_Float16)e3;
    hv[4] = (_Float16)e4; hv[5] = (_Float16)e5;
    hv[6] = (_Float16)e6; hv[7] = (_Float16)e7;
    *(half8*)&pb[r][kcol2] = hv;
    float sum = ((e0 + e1) + (e2 + e3)) + ((e4 + e5) + (e6 + e7));
    #pragma unroll
    for (int off = 16; off > 0; off >>= 1)
      sum += __shfl_xor(sum, off);
    if (ll == 0) red[wave][r] = sum;
  };

  #pragma unroll
  for (int i = 0; i < 2; ++i) {       // bank B (rows 4..7) in flight over proc A
    const float* p = sphp + (bhS + q0 + 4 + 2 * i + lh) * S_DIM + kcol2;
    sB[i][0] = *(const f32x4*)p;
    sB[i][1] = *(const f32x4*)(p + 4);
  }
  proc(0, sA[0], mb[0]);
  proc(1, sA[1], mb[1]);
  proc(2, sB[0], mb[2]);
  proc(3, sB[1], mb[3]);

  __syncthreads();   // the ONLY barrier: pb (all k-spans) + red now final

  // ---------- Phase 2d: p = e/sum -> nontemporal fp32 stores (keep L3 for sph) --
  #pragma unroll
  for (int i = 0; i < 4; ++i) {
    const int r = 2 * i + lh;
    const float inv = __builtin_amdgcn_rcpf(
        (red[0][r] + red[1][r]) + (red[2][r] + red[3][r]));
    half8 e = *(half8*)&pb[r][kcol2];
    f32x4 p0, p1;
    p0.x = (float)e[0] * inv; p0.y = (float)e[1] * inv;
    p0.z = (float)e[2] * inv; p0.w = (float)e[3] * inv;
    p1.x = (float)e[4] * inv; p1.y = (float)e[5] * inv;
    p1.z = (float)e[6] * inv; p1.w = (float)e[7] * inv;
    float* dst = pp + (bhS + q0 + r) * S_DIM + kcol2;
    __builtin_nontemporal_store(p0, (f32x4*)dst);
    __builtin_nontemporal_store(p1, (f32x4*)(dst + 4));
  }

  // ---------- Phase 3: O^T = V^T E^T; A-operand straight from L2-resident V^T ----
  f32x4 oacc = {0.f, 0.f, 0.f, 0.f};
  const _Float16* vrow = vt16 + ((size_t)bh * 64 + wave * 16 + row16) * S_DIM + quad * 8;
  #pragma unroll 8
  for (int c = 0; c < 32; ++c) {
    half8 af = *(const half8*)(vrow + c * 32);
    half8 bf = *(const half8*)&pb[row8][c * 32 + quad * 8];
    oacc = __builtin_amdgcn_mfma_f32_16x16x32_f16(af, bf, oacc, 0, 0, 0);
  }

  if (row16 < 8) {
    const float ssum = (red[0][row8] + red[1][row8]) + (red[2][row8] + red[3][row8]);
    const float invq = __builtin_amdgcn_rcpf(ssum);
    float* orow = outp + (bhS + q0 + row8) * 64 + wave * 16 + quad * 4;
    *(f32x4*)orow = oacc * invq;
  }
}

extern "C" void kernel_launch(void* const* d_in, const int* in_sizes, int n_in,
                              void* d_out, int out_size, void* d_ws, size_t ws_size,
                              hipStream_t stream) {
  const float* q    = (const float*)d_in[0];
  const float* k    = (const float*)d_in[1];
  const float* v    = (const float*)d_in[2];
  const float* sph  = (const float*)d_in[3];
  const int*   mask = (const int*)d_in[4];
  float* out  = (float*)d_out;                          // [4,8,1024,64]
  float* patt = out + (size_t)4 * 8 * 1024 * 64;        // [4,8,1024,1024]

  _Float16* k16  = (_Float16*)d_ws;                     // 4 MiB
  _Float16* vt16 = k16 + (size_t)32 * S_DIM * 64;       // 4 MiB
  unsigned int* pm = (unsigned int*)(vt16 + (size_t)32 * S_DIM * 64);  // 512 KiB

  hipLaunchKernelGGL(maskpack_kernel, dim3(4 * S_DIM), dim3(256), 0, stream,
                     mask, pm);
  hipLaunchKernelGGL(prep_kernel, dim3(32 * 16), dim3(256), 0, stream,
                     k, v, k16, vt16);
  hipLaunchKernelGGL(sdpa_kernel, dim3(32 * 128), dim3(256), 0, stream,
                     q, k16, vt16, sph, pm, out, patt);
}

// Round 7
// 321.827 us; speedup vs baseline: 1.1235x; 1.1235x over previous
//
#include <hip/hip_runtime.h>

#define S_DIM 1024
#define TQ 16
#define QS 0.180336880f   // (1/8) * log2(e): folds temperature and exp2 conversion

typedef __attribute__((ext_vector_type(4))) float f32x4;
typedef _Float16 half4 __attribute__((ext_vector_type(4)));
typedef _Float16 half8 __attribute__((ext_vector_type(8)));

__device__ __forceinline__ half8 pack8h(f32x4 a, f32x4 b) {
  half8 r;
  r[0] = (_Float16)a.x; r[1] = (_Float16)a.y;
  r[2] = (_Float16)a.z; r[3] = (_Float16)a.w;
  r[4] = (_Float16)b.x; r[5] = (_Float16)b.y;
  r[6] = (_Float16)b.z; r[7] = (_Float16)b.w;
  return r;
}

// async global->LDS DMA, 16B per lane: per-lane global src, wave-uniform LDS base
__device__ __forceinline__ void dma16(const float* gsrc, float* ldst) {
  __builtin_amdgcn_global_load_lds(
      (const __attribute__((address_space(1))) unsigned int*)gsrc,
      (__attribute__((address_space(3))) unsigned int*)ldst, 16, 0, 0);
}

// ---------- prep: K -> f16 (same layout), V -> f16 transposed [bh][d][k] ----------
__global__ __launch_bounds__(256)
void prep_kernel(const float* __restrict__ kp, const float* __restrict__ vp,
                 _Float16* __restrict__ k16, _Float16* __restrict__ vt16)
{
  __shared__ _Float16 tile[64][72];
  const int tid = threadIdx.x;
  const int bh  = blockIdx.x >> 4;             // 32 (b,h) pairs
  const int c0  = (blockIdx.x & 15) * 64;      // 64-row k-chunk
  const size_t base = ((size_t)bh * S_DIM + c0) * 64;

  #pragma unroll
  for (int i = 0; i < 4; ++i) {
    const int idx = i * 256 + tid;
    f32x4 kv = *(const f32x4*)(kp + base + (size_t)idx * 4);
    half4 h; h[0] = (_Float16)kv.x; h[1] = (_Float16)kv.y;
    h[2] = (_Float16)kv.z; h[3] = (_Float16)kv.w;
    *(half4*)(k16 + base + (size_t)idx * 4) = h;
  }
  #pragma unroll
  for (int i = 0; i < 4; ++i) {
    const int idx = i * 256 + tid;
    const int r = idx >> 4, c4 = idx & 15;
    f32x4 vv = *(const f32x4*)(vp + base + (size_t)r * 64 + c4 * 4);
    tile[c4 * 4 + 0][r] = (_Float16)vv.x;
    tile[c4 * 4 + 1][r] = (_Float16)vv.y;
    tile[c4 * 4 + 2][r] = (_Float16)vv.z;
    tile[c4 * 4 + 3][r] = (_Float16)vv.w;
  }
  __syncthreads();
  #pragma unroll
  for (int i = 0; i < 2; ++i) {
    const int idx = i * 256 + tid;
    const int d = idx >> 3, g = idx & 7;
    half8 h = *(half8*)&tile[d][g * 8];
    *(half8*)(vt16 + ((size_t)bh * 64 + d) * S_DIM + c0 + g * 8) = h;
  }
}

// ---------- maskpack: mask[b][row][k] i32 -> pm[b*S+row][32] bit-dwords ----------
__global__ __launch_bounds__(256)
void maskpack_kernel(const int* __restrict__ maskp, unsigned int* __restrict__ pm)
{
  const int tid  = threadIdx.x;
  const int lane = tid & 63;
  const int wave = tid >> 6;
  const int row  = blockIdx.x;                 // 4096 rows (b*1024 + r)
  const size_t base = (size_t)row * S_DIM + wave * 256;
  unsigned long long bal0, bal1, bal2, bal3;
  bal0 = __ballot(maskp[base +   0 + lane] != 0);
  bal1 = __ballot(maskp[base +  64 + lane] != 0);
  bal2 = __ballot(maskp[base + 128 + lane] != 0);
  bal3 = __ballot(maskp[base + 192 + lane] != 0);
  if (lane == 0) {
    unsigned long long* dst =
        (unsigned long long*)(pm + (size_t)row * 32 + wave * 8);
    dst[0] = bal0; dst[1] = bal1; dst[2] = bal2; dst[3] = bal3;
  }
}

// ---------- main: merged QK^T+softmax loop with LDS-DMA sph pipeline ----------
__global__ __launch_bounds__(256, 3)
void sdpa_kernel(const float* __restrict__ qp,
                 const _Float16* __restrict__ k16,
                 const _Float16* __restrict__ vt16,
                 const float* __restrict__ sphp,
                 const unsigned int* __restrict__ pm,
                 float* __restrict__ outp, float* __restrict__ pp)
{
  __shared__ _Float16 pb[TQ][1032];      // e (f16) exchange       33024 B
  __shared__ float    sstage[4][4][256]; // sph DMA ring, 1KB/slot 16384 B
  __shared__ float    red[4][TQ];        // per-wave row sums        256 B

  const int tid   = threadIdx.x;
  const int lane  = tid & 63;
  const int wave  = tid >> 6;
  const int row16 = lane & 15;        // MFMA m/n index = q-local
  const int quad  = lane >> 4;        // MFMA k-chunk / C row-quad

  const int bh = blockIdx.x >> 6;     // 32 (b,h) pairs
  const int qt = blockIdx.x & 63;     // 64 q-tiles of 16 rows
  const int b  = bh >> 3;             // H=8
  const int q0 = qt * TQ;
  const size_t bhS = (size_t)bh * S_DIM;
  const int kb = wave * 256;          // wave-private 256-k span

  // ---- mask bits: lane's row q0+row16, own k-span = 8 dwords, loaded once ----
  const unsigned int* pmrow = pm + ((size_t)b * S_DIM + q0 + row16) * 32 + wave * 8;
  unsigned int mb[8];
  #pragma unroll
  for (int i = 0; i < 8; ++i) mb[i] = pmrow[i];

  // ---- Q fragment, pre-scaled by (1/8)*log2e ----
  const float* qrow = qp + (bhS + q0 + row16) * 64 + quad * 8;
  const f32x4 qs = {QS, QS, QS, QS};
  f32x4 qa = *(const f32x4*)(qrow);
  f32x4 qb = *(const f32x4*)(qrow + 4);
  f32x4 qc = *(const f32x4*)(qrow + 32);
  f32x4 qd = *(const f32x4*)(qrow + 36);
  const half8 bq0 = pack8h(qa * qs, qb * qs);
  const half8 bq1 = pack8h(qc * qs, qd * qs);

  const _Float16* kbp = k16 + (bhS + kb) * 64;
  // per-lane sph source: row q0+row16, col kb+quad*4 (+16 per step)
  const float* sph_lane = sphp + (bhS + q0 + row16) * S_DIM + kb + quad * 4;

  half8 kA0[4], kA1[4];               // K register ring (static idx only)
  float lanesum = 0.f;

  // Prefetch step T: sph DMA into ring slot + K rows into register ring.
  #define PREF(T) do {                                                        \
    dma16(sph_lane + (T) * 16, &sstage[wave][(T) & 3][0]);                    \
    const _Float16* krow_ = kbp + ((T) * 16 + row16) * 64 + quad * 8;         \
    kA0[(T) & 3] = *(const half8*)(krow_);                                    \
    kA1[(T) & 3] = *(const half8*)(krow_ + 32);                               \
  } while (0)

  // One merged step: wait counted vmcnt (never 0 mid-loop), consume sph(T)
  // from LDS ring, MFMA scores, exp2, e -> pb, accumulate row sum.
  #define STEP(T, WN) do {                                                    \
    if ((T) + 3 < 16) { PREF((T) + 3); }                                      \
    asm volatile("s_waitcnt vmcnt(" #WN ") lgkmcnt(0)" ::: "memory");         \
    f32x4 s4 = *(const f32x4*)&sstage[wave][(T) & 3][lane * 4];               \
    f32x4 acc = {0.f, 0.f, 0.f, 0.f};                                         \
    acc = __builtin_amdgcn_mfma_f32_16x16x32_f16(kA0[(T) & 3], bq0, acc, 0, 0, 0); \
    acc = __builtin_amdgcn_mfma_f32_16x16x32_f16(kA1[(T) & 3], bq1, acc, 0, 0, 0); \
    const unsigned int m4 = (mb[(T) >> 1] >> (((T) & 1) * 16 + quad * 4)) & 0xFu; \
    float e0 = (m4 & 1u) ? __builtin_amdgcn_exp2f(acc.x * s4.x) : 0.f;        \
    float e1 = (m4 & 2u) ? __builtin_amdgcn_exp2f(acc.y * s4.y) : 0.f;        \
    float e2 = (m4 & 4u) ? __builtin_amdgcn_exp2f(acc.z * s4.z) : 0.f;        \
    float e3 = (m4 & 8u) ? __builtin_amdgcn_exp2f(acc.w * s4.w) : 0.f;        \
    half4 hv; hv[0] = (_Float16)e0; hv[1] = (_Float16)e1;                     \
    hv[2] = (_Float16)e2; hv[3] = (_Float16)e3;                               \
    *(half4*)&pb[row16][kb + (T) * 16 + quad * 4] = hv;                       \
    lanesum += (e0 + e1) + (e2 + e3);                                         \
  } while (0)

  // Prologue: 3 prefetch windows (empty asm pins window boundaries so the
  // conservative vmcnt counts below hold under any in-window reordering).
  PREF(0); asm volatile("" ::: "memory");
  PREF(1); asm volatile("" ::: "memory");
  PREF(2); asm volatile("" ::: "memory");

  // Steady state: 3 newer windows x 3 vmem ops = vmcnt(9). Tail: 6/3/0.
  STEP( 0, 9); STEP( 1, 9); STEP( 2, 9); STEP( 3, 9);
  STEP( 4, 9); STEP( 5, 9); STEP( 6, 9); STEP( 7, 9);
  STEP( 8, 9); STEP( 9, 9); STEP(10, 9); STEP(11, 9);
  STEP(12, 9); STEP(13, 6); STEP(14, 3); STEP(15, 0);
  #undef STEP
  #undef PREF

  // Row sum: all of a lane's 64 e-values share q=row16 -> only quad-reduce.
  lanesum += __shfl_xor(lanesum, 16);
  lanesum += __shfl_xor(lanesum, 32);
  if (lane < 16) red[wave][lane] = lanesum;

  __syncthreads();   // the ONLY barrier: pb (all k-spans) + red now final

  // ---------- p = e/sum -> coalesced nontemporal fp32 stores ----------
  const int ll = lane & 31;
  const int lh = lane >> 5;
  const int kcol2 = kb + ll * 8;
  #pragma unroll
  for (int i = 0; i < 8; ++i) {
    const int r = 2 * i + lh;
    const float inv = __builtin_amdgcn_rcpf(
        (red[0][r] + red[1][r]) + (red[2][r] + red[3][r]));
    half8 e = *(half8*)&pb[r][kcol2];
    f32x4 p0, p1;
    p0.x = (float)e[0] * inv; p0.y = (float)e[1] * inv;
    p0.z = (float)e[2] * inv; p0.w = (float)e[3] * inv;
    p1.x = (float)e[4] * inv; p1.y = (float)e[5] * inv;
    p1.z = (float)e[6] * inv; p1.w = (float)e[7] * inv;
    float* dst = pp + (bhS + q0 + r) * S_DIM + kcol2;
    __builtin_nontemporal_store(p0, (f32x4*)dst);
    __builtin_nontemporal_store(p1, (f32x4*)(dst + 4));
  }

  // ---------- O^T = V^T E^T; A-operand straight from L2-resident V^T ----------
  f32x4 oacc = {0.f, 0.f, 0.f, 0.f};
  const _Float16* vrow = vt16 + ((size_t)bh * 64 + wave * 16 + row16) * S_DIM + quad * 8;
  #pragma unroll 8
  for (int c = 0; c < 32; ++c) {
    half8 af = *(const half8*)(vrow + c * 32);
    half8 bf = *(const half8*)&pb[row16][c * 32 + quad * 8];
    oacc = __builtin_amdgcn_mfma_f32_16x16x32_f16(af, bf, oacc, 0, 0, 0);
  }

  // O^T C-layout: col=row16=q, row=quad*4+r=d-local; fold 1/sum here.
  const float ssum = (red[0][row16] + red[1][row16]) + (red[2][row16] + red[3][row16]);
  const float invq = __builtin_amdgcn_rcpf(ssum);
  float* orow = outp + (bhS + q0 + row16) * 64 + wave * 16 + quad * 4;
  *(f32x4*)orow = oacc * invq;
}

extern "C" void kernel_launch(void* const* d_in, const int* in_sizes, int n_in,
                              void* d_out, int out_size, void* d_ws, size_t ws_size,
                              hipStream_t stream) {
  const float* q    = (const float*)d_in[0];
  const float* k    = (const float*)d_in[1];
  const float* v    = (const float*)d_in[2];
  const float* sph  = (const float*)d_in[3];
  const int*   mask = (const int*)d_in[4];
  float* out  = (float*)d_out;                          // [4,8,1024,64]
  float* patt = out + (size_t)4 * 8 * 1024 * 64;        // [4,8,1024,1024]

  _Float16* k16  = (_Float16*)d_ws;                     // 4 MiB
  _Float16* vt16 = k16 + (size_t)32 * S_DIM * 64;       // 4 MiB
  unsigned int* pm = (unsigned int*)(vt16 + (size_t)32 * S_DIM * 64);  // 512 KiB

  hipLaunchKernelGGL(maskpack_kernel, dim3(4 * S_DIM), dim3(256), 0, stream,
                     mask, pm);
  hipLaunchKernelGGL(prep_kernel, dim3(32 * 16), dim3(256), 0, stream,
                     k, v, k16, vt16);
  hipLaunchKernelGGL(sdpa_kernel, dim3(32 * 64), dim3(256), 0, stream,
                     q, k16, vt16, sph, pm, out, patt);
}